// Round 1
// baseline (1532.458 us; speedup 1.0000x reference)
//
#include <hip/hip_runtime.h>
#include <math.h>

// B=16, P=4096, D=512, G=64, N_IMGS=5000, TEMP=0.01
// M = B*P = 65536 rows, K = N = D = 512.

// C[m,n] = bias[n] + sum_k A[m,k] * W[n,k]
// A: (M,512) row-major; W: (512,512) row-major (we need x @ W^T).
// 64x64 block tile, BK=16, 256 threads, 4x4 microtile per thread.
__global__ __launch_bounds__(256) void gemm_nt_bias(
    const float* __restrict__ A, const float* __restrict__ W,
    const float* __restrict__ bias, float* __restrict__ C)
{
    const int K = 512, N = 512;
    __shared__ float As[16][68];  // [k][m], padded row (68*4B = 272B, 16B-aligned)
    __shared__ float Ws[16][68];  // [k][n]

    const int m0 = blockIdx.x * 64;
    const int n0 = blockIdx.y * 64;
    const int tid = threadIdx.x;
    const int lrow = tid >> 2;         // 0..63 (tile row to load)
    const int lkq  = (tid & 3) << 2;   // 0,4,8,12 (k quad to load)
    const int mb = (tid >> 4) << 2;    // 0..60 microtile row base
    const int nb = (tid & 15) << 2;    // 0..60 microtile col base

    const float* Aptr = A + (size_t)(m0 + lrow) * K + lkq;
    const float* Wptr = W + (size_t)(n0 + lrow) * K + lkq;

    float acc[4][4] = {};
    float4 av = *(const float4*)Aptr;
    float4 wv = *(const float4*)Wptr;

    for (int k0 = 0; k0 < K; k0 += 16) {
        __syncthreads();
        As[lkq + 0][lrow] = av.x; As[lkq + 1][lrow] = av.y;
        As[lkq + 2][lrow] = av.z; As[lkq + 3][lrow] = av.w;
        Ws[lkq + 0][lrow] = wv.x; Ws[lkq + 1][lrow] = wv.y;
        Ws[lkq + 2][lrow] = wv.z; Ws[lkq + 3][lrow] = wv.w;
        __syncthreads();
        if (k0 + 16 < K) {  // prefetch next K-tile while computing
            av = *(const float4*)(Aptr + k0 + 16);
            wv = *(const float4*)(Wptr + k0 + 16);
        }
        #pragma unroll
        for (int kk = 0; kk < 16; ++kk) {
            float4 a4 = *(const float4*)&As[kk][mb];
            float4 b4 = *(const float4*)&Ws[kk][nb];
            const float ar[4] = {a4.x, a4.y, a4.z, a4.w};
            const float br[4] = {b4.x, b4.y, b4.z, b4.w};
            #pragma unroll
            for (int i = 0; i < 4; ++i)
                #pragma unroll
                for (int j = 0; j < 4; ++j)
                    acc[i][j] = fmaf(ar[i], br[j], acc[i][j]);
        }
    }

    #pragma unroll
    for (int i = 0; i < 4; ++i) {
        float4 o;
        o.x = acc[i][0] + bias[n0 + nb + 0];
        o.y = acc[i][1] + bias[n0 + nb + 1];
        o.z = acc[i][2] + bias[n0 + nb + 2];
        o.w = acc[i][3] + bias[n0 + nb + 3];
        *(float4*)&C[(size_t)(m0 + mb + i) * N + (n0 + nb)] = o;
    }
}

// One wave per sample point. q lives in qout (read whole row, then overwritten).
// grid reshape semantics: flat f = g1*128 + g2*2 + c over the (2,4096) block:
//   channel = f>>12 (0 -> sample_x, 1 -> sample_y), p = f&4095.
__global__ __launch_bounds__(256) void sample_attn(
    float* qout,                       // (B,P,512): q in, attention out
    const float* __restrict__ kbuf,    // (B,P,512)
    const float* __restrict__ vbuf,    // (B,P,512)
    const float* __restrict__ avgs,    // (N_IMGS,2,P)
    const float* __restrict__ stds,    // (N_IMGS,2,P)
    const float* __restrict__ nx,      // (B,1,P)
    const float* __restrict__ ny,      // (B,1,P)
    const int* __restrict__ img_ids)   // (B,)
{
    const int lane = threadIdx.x & 63;
    const int wid  = threadIdx.x >> 6;
    const int point = (blockIdx.x << 2) + wid;
    const int b = point >> 12;
    const int n = point & 4095;
    const int g1 = n >> 6, g2 = n & 63;
    const int f0 = g1 * 128 + g2 * 2;
    const int id = img_ids[b];

    float g[2];
    #pragma unroll
    for (int c = 0; c < 2; ++c) {
        int f = f0 + c;
        int ch = f >> 12;
        int p  = f & 4095;
        float noise = ch ? ny[(size_t)b * 4096 + p] : nx[(size_t)b * 4096 + p];
        size_t o = ((size_t)id * 2 + ch) * 4096 + p;
        g[c] = tanhf((noise + avgs[o]) * stds[o]);
    }

    // align_corners=False pixel mapping, H=W=64
    float ix = (g[0] + 1.0f) * 32.0f - 0.5f;
    float iy = (g[1] + 1.0f) * 32.0f - 0.5f;
    float fx0 = floorf(ix), fy0 = floorf(iy);
    float wx1 = ix - fx0, wx0 = 1.0f - wx1;
    float wy1 = iy - fy0, wy0 = 1.0f - wy1;
    int x0 = (int)fx0, y0 = (int)fy0;
    int x1 = x0 + 1, y1 = y0 + 1;
    bool vx0 = (x0 >= 0) & (x0 < 64), vx1 = (x1 >= 0) & (x1 < 64);
    bool vy0 = (y0 >= 0) & (y0 < 64), vy1 = (y1 >= 0) & (y1 < 64);
    float w00 = (vx0 & vy0) ? wx0 * wy0 : 0.0f;
    float w10 = (vx1 & vy0) ? wx1 * wy0 : 0.0f;
    float w01 = (vx0 & vy1) ? wx0 * wy1 : 0.0f;
    float w11 = (vx1 & vy1) ? wx1 * wy1 : 0.0f;
    int cx0 = min(max(x0, 0), 63), cx1 = min(max(x1, 0), 63);
    int cy0 = min(max(y0, 0), 63), cy1 = min(max(y1, 0), 63);

    const size_t base = (size_t)b * 4096 * 512;
    const size_t r00 = base + (size_t)(cy0 * 64 + cx0) * 512;
    const size_t r10 = base + (size_t)(cy0 * 64 + cx1) * 512;
    const size_t r01 = base + (size_t)(cy1 * 64 + cx0) * 512;
    const size_t r11 = base + (size_t)(cy1 * 64 + cx1) * 512;

    float* qrow = qout + base + (size_t)n * 512;
    const int c0 = lane * 4;
    const int c1 = 256 + lane * 4;

    float4 q0 = *(const float4*)(qrow + c0);
    float4 q1 = *(const float4*)(qrow + c1);

    #define BLEND(buf, r, c, dst)                                     \
        {                                                             \
            float4 p00 = *(const float4*)(buf + r00 + (c));           \
            float4 p10 = *(const float4*)(buf + r10 + (c));           \
            float4 p01 = *(const float4*)(buf + r01 + (c));           \
            float4 p11 = *(const float4*)(buf + r11 + (c));           \
            dst.x = w00 * p00.x + w10 * p10.x + w01 * p01.x + w11 * p11.x; \
            dst.y = w00 * p00.y + w10 * p10.y + w01 * p01.y + w11 * p11.y; \
            dst.z = w00 * p00.z + w10 * p10.z + w01 * p01.z + w11 * p11.z; \
            dst.w = w00 * p00.w + w10 * p10.w + w01 * p01.w + w11 * p11.w; \
        }

    float4 sk0, sk1, sv0, sv1;
    BLEND(kbuf, r, c0, sk0);
    BLEND(kbuf, r, c1, sk1);
    BLEND(vbuf, r, c0, sv0);
    BLEND(vbuf, r, c1, sv1);
    #undef BLEND

    float score = q0.x * sk0.x + q0.y * sk0.y + q0.z * sk0.z + q0.w * sk0.w
                + q1.x * sk1.x + q1.y * sk1.y + q1.z * sk1.z + q1.w * sk1.w;
    #pragma unroll
    for (int off = 32; off > 0; off >>= 1)
        score += __shfl_xor(score, off);

    float sig = 1.0f / (1.0f + expf(-0.01f * score));
    float4 oA, oB;
    oA.x = sig * sv0.x; oA.y = sig * sv0.y; oA.z = sig * sv0.z; oA.w = sig * sv0.w;
    oB.x = sig * sv1.x; oB.y = sig * sv1.y; oB.z = sig * sv1.z; oB.w = sig * sv1.w;
    *(float4*)(qrow + c0) = oA;
    *(float4*)(qrow + c1) = oB;
}

extern "C" void kernel_launch(void* const* d_in, const int* in_sizes, int n_in,
                              void* d_out, int out_size, void* d_ws, size_t ws_size,
                              hipStream_t stream)
{
    const float* x    = (const float*)d_in[0];
    const float* Wq   = (const float*)d_in[1];
    const float* bq   = (const float*)d_in[2];
    const float* Wk   = (const float*)d_in[3];
    const float* bk   = (const float*)d_in[4];
    const float* Wv   = (const float*)d_in[5];
    const float* bv   = (const float*)d_in[6];
    const float* avgs = (const float*)d_in[7];
    const float* stds = (const float*)d_in[8];
    const float* nx   = (const float*)d_in[9];
    const float* ny   = (const float*)d_in[10];
    const int* img_ids = (const int*)d_in[11];
    // d_in[12] = mask: unused by the reference.

    float* out  = (float*)d_out;                       // holds q, then attention
    float* kbuf = (float*)d_ws;                        // 65536*512 fp32 = 134 MB
    float* vbuf = kbuf + (size_t)65536 * 512;          // +134 MB

    dim3 ggrid(65536 / 64, 512 / 64);
    gemm_nt_bias<<<ggrid, 256, 0, stream>>>(x, Wq, bq, out);
    gemm_nt_bias<<<ggrid, 256, 0, stream>>>(x, Wk, bk, kbuf);
    gemm_nt_bias<<<ggrid, 256, 0, stream>>>(x, Wv, bv, vbuf);

    sample_attn<<<65536 / 4, 256, 0, stream>>>(out, kbuf, vbuf,
                                               avgs, stds, nx, ny, img_ids);
}

// Round 2
// 378.113 us; speedup vs baseline: 4.0529x; 4.0529x over previous
//
#include <hip/hip_runtime.h>
#include <math.h>

// B=16, P=4096, D=512, G=64, N_IMGS=5000, TEMP=0.01
// M = 65536, K = 512, fused N = 1536 (q|k|v).

typedef __attribute__((ext_vector_type(8))) short s16x8;   // 8 bf16 (4 VGPRs)
typedef __attribute__((ext_vector_type(4))) float f32x4;

__device__ __forceinline__ unsigned short f2bf(float f) {
    unsigned u = __float_as_uint(f);
    u += 0x7FFFu + ((u >> 16) & 1u);   // RNE
    return (unsigned short)(u >> 16);
}

__device__ __forceinline__ void gload_lds16(const void* g, void* l) {
    __builtin_amdgcn_global_load_lds(
        (const __attribute__((address_space(1))) unsigned int*)g,
        (__attribute__((address_space(3))) unsigned int*)l, 16, 0, 0);
}

// ---------- fp32 -> bf16 conversion (8 elems / thread) ----------
__global__ __launch_bounds__(256) void cvt_bf16x8(
    const float* __restrict__ src, unsigned short* __restrict__ dst, int n8)
{
    int i = blockIdx.x * 256 + threadIdx.x;
    if (i >= n8) return;
    const float4* s = (const float4*)src + 2 * (size_t)i;
    float4 a = s[0], b = s[1];
    uint4 o;
    o.x = (unsigned)f2bf(a.x) | ((unsigned)f2bf(a.y) << 16);
    o.y = (unsigned)f2bf(a.z) | ((unsigned)f2bf(a.w) << 16);
    o.z = (unsigned)f2bf(b.x) | ((unsigned)f2bf(b.y) << 16);
    o.w = (unsigned)f2bf(b.z) | ((unsigned)f2bf(b.w) << 16);
    ((uint4*)dst)[i] = o;
}

// ---------- fused QKV GEMM: C[m, n] = sum_k x[m,k] * W[n,k] + bias[n] ----------
// 128x128 tile, BK=32, 256 threads (4 waves, 2x2), 4x4 MFMA frags / wave.
// LDS tile layout (per buf): A = [kg:4][row:128][8] bf16 at byte 0,
//                            B = same at byte 8192. Buf stride 16384 B.
__global__ __launch_bounds__(256) void qkv_gemm(
    const unsigned short* __restrict__ xbf,   // (65536,512) bf16
    const unsigned short* __restrict__ wbf,   // (1536,512) bf16 (Wq|Wk|Wv)
    const float* __restrict__ bq, const float* __restrict__ bk,
    const float* __restrict__ bv,
    float* __restrict__ qout,                 // (65536,512) f32
    unsigned short* __restrict__ kbf,         // (65536,512) bf16
    unsigned short* __restrict__ vbf)
{
    __shared__ __align__(16) short lds[2][8192];

    const int tid  = threadIdx.x;
    const int lane = tid & 63, wid = tid >> 6;
    const int wr = wid >> 1, wc = wid & 1;

    const int bid = blockIdx.x;
    const int mt = bid / 12, nt = bid % 12;   // m-major: consecutive blocks share W panel
    const int m0 = mt * 128, n0 = nt * 128;

    // staging: issue q in {0,1}: kg = q*2 + (tid>>7), row = tid&127,
    // LDS byte (within region) = q*4096 + tid*16.
    const int srow = tid & 127;
    const int skg  = tid >> 7;
    const unsigned short* a0 = xbf + (size_t)(m0 + srow) * 512 + skg * 8;
    const unsigned short* a1 = a0 + 16;       // kg + 2  -> +16 elems
    const unsigned short* b0 = wbf + (size_t)(n0 + srow) * 512 + skg * 8;
    const unsigned short* b1 = b0 + 16;
    char* ldsc = (char*)lds;
    const int dA0 = tid * 16, dA1 = 4096 + tid * 16;
    const int dB0 = 8192 + tid * 16, dB1 = 12288 + tid * 16;

    f32x4 acc[4][4] = {};

    const int abase = (lane >> 4) * 2048 + (wr * 64 + (lane & 15)) * 16;
    const int bbase = 8192 + (lane >> 4) * 2048 + (wc * 64 + (lane & 15)) * 16;

    // prologue stage k0 = 0 into buf 0
    gload_lds16(a0, ldsc + dA0);
    gload_lds16(a1, ldsc + dA1);
    gload_lds16(b0, ldsc + dB0);
    gload_lds16(b1, ldsc + dB1);

    for (int it = 0; it < 16; ++it) {
        const int buf = it & 1;
        __syncthreads();                       // drains vmcnt: buf's tile ready
        if (it < 15) {                         // prefetch next tile into buf^1
            const int k0 = (it + 1) * 32;
            const int bo = (buf ^ 1) * 16384;
            gload_lds16(a0 + k0, ldsc + bo + dA0);
            gload_lds16(a1 + k0, ldsc + bo + dA1);
            gload_lds16(b0 + k0, ldsc + bo + dB0);
            gload_lds16(b1 + k0, ldsc + bo + dB1);
        }
        const char* lp = ldsc + buf * 16384;
        s16x8 af[4], bfr[4];
        #pragma unroll
        for (int i = 0; i < 4; ++i) af[i]  = *(const s16x8*)(lp + abase + i * 256);
        #pragma unroll
        for (int j = 0; j < 4; ++j) bfr[j] = *(const s16x8*)(lp + bbase + j * 256);
        #pragma unroll
        for (int i = 0; i < 4; ++i)
            #pragma unroll
            for (int j = 0; j < 4; ++j)
                acc[i][j] = __builtin_amdgcn_mfma_f32_16x16x32_bf16(
                    af[i], bfr[j], acc[i][j], 0, 0, 0);
    }

    // epilogue: C/D layout col = lane&15, row = (lane>>4)*4 + reg
    const int sel = nt >> 2;                   // 0=q, 1=k, 2=v
    const float* bias = sel == 0 ? bq : (sel == 1 ? bk : bv);
    const int colg = (n0 & 511) + wc * 64 + (lane & 15);   // col within matrix
    const int rowg = m0 + wr * 64 + (lane >> 4) * 4;

    if (sel == 0) {
        #pragma unroll
        for (int i = 0; i < 4; ++i)
            #pragma unroll
            for (int j = 0; j < 4; ++j) {
                const float bb = bias[colg + j * 16];
                #pragma unroll
                for (int r = 0; r < 4; ++r)
                    qout[(size_t)(rowg + i * 16 + r) * 512 + colg + j * 16] =
                        acc[i][j][r] + bb;
            }
    } else {
        unsigned short* dst = (sel == 1) ? kbf : vbf;
        #pragma unroll
        for (int i = 0; i < 4; ++i)
            #pragma unroll
            for (int j = 0; j < 4; ++j) {
                const float bb = bias[colg + j * 16];
                #pragma unroll
                for (int r = 0; r < 4; ++r)
                    dst[(size_t)(rowg + i * 16 + r) * 512 + colg + j * 16] =
                        f2bf(acc[i][j][r] + bb);
            }
    }
}

// ---------- grid-sample + gated attention ----------
// One wave per point; lane covers cols lane*8 .. lane*8+7.
__global__ __launch_bounds__(256) void sample_attn(
    float* __restrict__ qo,                 // (B,P,512) f32: q in, attention out
    const unsigned short* __restrict__ kbf, // (B,P,512) bf16
    const unsigned short* __restrict__ vbf,
    const float* __restrict__ avgs,         // (N_IMGS,2,P)
    const float* __restrict__ stds,
    const float* __restrict__ nx,           // (B,1,P)
    const float* __restrict__ ny,
    const int* __restrict__ img_ids)
{
    const int lane = threadIdx.x & 63;
    const int wid  = threadIdx.x >> 6;
    const int point = (blockIdx.x << 2) + wid;
    const int b = point >> 12;
    const int n = point & 4095;
    const int g1 = n >> 6, g2 = n & 63;
    const int f0 = g1 * 128 + g2 * 2;
    const int id = img_ids[b];

    float g[2];
    #pragma unroll
    for (int c = 0; c < 2; ++c) {
        int f = f0 + c;
        int ch = f >> 12;
        int p  = f & 4095;
        float noise = ch ? ny[(size_t)b * 4096 + p] : nx[(size_t)b * 4096 + p];
        size_t o = ((size_t)id * 2 + ch) * 4096 + p;
        g[c] = tanhf((noise + avgs[o]) * stds[o]);
    }

    float ix = (g[0] + 1.0f) * 32.0f - 0.5f;
    float iy = (g[1] + 1.0f) * 32.0f - 0.5f;
    float fx0 = floorf(ix), fy0 = floorf(iy);
    float wx1 = ix - fx0, wx0 = 1.0f - wx1;
    float wy1 = iy - fy0, wy0 = 1.0f - wy1;
    int x0 = (int)fx0, y0 = (int)fy0;
    int x1 = x0 + 1, y1 = y0 + 1;
    bool vx0 = (x0 >= 0) & (x0 < 64), vx1 = (x1 >= 0) & (x1 < 64);
    bool vy0 = (y0 >= 0) & (y0 < 64), vy1 = (y1 >= 0) & (y1 < 64);
    float w00 = (vx0 & vy0) ? wx0 * wy0 : 0.0f;
    float w10 = (vx1 & vy0) ? wx1 * wy0 : 0.0f;
    float w01 = (vx0 & vy1) ? wx0 * wy1 : 0.0f;
    float w11 = (vx1 & vy1) ? wx1 * wy1 : 0.0f;
    int cx0 = min(max(x0, 0), 63), cx1 = min(max(x1, 0), 63);
    int cy0 = min(max(y0, 0), 63), cy1 = min(max(y1, 0), 63);

    const size_t base = (size_t)b * 4096 * 512;
    const size_t r00 = base + (size_t)(cy0 * 64 + cx0) * 512;
    const size_t r10 = base + (size_t)(cy0 * 64 + cx1) * 512;
    const size_t r01 = base + (size_t)(cy1 * 64 + cx0) * 512;
    const size_t r11 = base + (size_t)(cy1 * 64 + cx1) * 512;

    float* qrow = qo + base + (size_t)n * 512;
    const int c = lane * 8;

    float4 q0 = *(const float4*)(qrow + c);
    float4 q1 = *(const float4*)(qrow + c + 4);

    // gather 8 bf16 -> 8 f32 from the 4 corners, blend
    float sk[8], sv[8];
    {
        uint4 u00k = *(const uint4*)(kbf + r00 + c);
        uint4 u10k = *(const uint4*)(kbf + r10 + c);
        uint4 u01k = *(const uint4*)(kbf + r01 + c);
        uint4 u11k = *(const uint4*)(kbf + r11 + c);
        uint4 u00v = *(const uint4*)(vbf + r00 + c);
        uint4 u10v = *(const uint4*)(vbf + r10 + c);
        uint4 u01v = *(const uint4*)(vbf + r01 + c);
        uint4 u11v = *(const uint4*)(vbf + r11 + c);
        const unsigned* p00k = (const unsigned*)&u00k;
        const unsigned* p10k = (const unsigned*)&u10k;
        const unsigned* p01k = (const unsigned*)&u01k;
        const unsigned* p11k = (const unsigned*)&u11k;
        const unsigned* p00v = (const unsigned*)&u00v;
        const unsigned* p10v = (const unsigned*)&u10v;
        const unsigned* p01v = (const unsigned*)&u01v;
        const unsigned* p11v = (const unsigned*)&u11v;
        #pragma unroll
        for (int t = 0; t < 4; ++t) {
            float a00 = __uint_as_float(p00k[t] << 16);
            float b00 = __uint_as_float(p00k[t] & 0xFFFF0000u);
            float a10 = __uint_as_float(p10k[t] << 16);
            float b10 = __uint_as_float(p10k[t] & 0xFFFF0000u);
            float a01 = __uint_as_float(p01k[t] << 16);
            float b01 = __uint_as_float(p01k[t] & 0xFFFF0000u);
            float a11 = __uint_as_float(p11k[t] << 16);
            float b11 = __uint_as_float(p11k[t] & 0xFFFF0000u);
            sk[2 * t]     = w00 * a00 + w10 * a10 + w01 * a01 + w11 * a11;
            sk[2 * t + 1] = w00 * b00 + w10 * b10 + w01 * b01 + w11 * b11;
            a00 = __uint_as_float(p00v[t] << 16);
            b00 = __uint_as_float(p00v[t] & 0xFFFF0000u);
            a10 = __uint_as_float(p10v[t] << 16);
            b10 = __uint_as_float(p10v[t] & 0xFFFF0000u);
            a01 = __uint_as_float(p01v[t] << 16);
            b01 = __uint_as_float(p01v[t] & 0xFFFF0000u);
            a11 = __uint_as_float(p11v[t] << 16);
            b11 = __uint_as_float(p11v[t] & 0xFFFF0000u);
            sv[2 * t]     = w00 * a00 + w10 * a10 + w01 * a01 + w11 * a11;
            sv[2 * t + 1] = w00 * b00 + w10 * b10 + w01 * b01 + w11 * b11;
        }
    }

    const float qv[8] = {q0.x, q0.y, q0.z, q0.w, q1.x, q1.y, q1.z, q1.w};
    float score = 0.0f;
    #pragma unroll
    for (int t = 0; t < 8; ++t) score += qv[t] * sk[t];
    #pragma unroll
    for (int off = 32; off > 0; off >>= 1)
        score += __shfl_xor(score, off);

    const float sig = 1.0f / (1.0f + expf(-0.01f * score));
    float4 oA, oB;
    oA.x = sig * sv[0]; oA.y = sig * sv[1]; oA.z = sig * sv[2]; oA.w = sig * sv[3];
    oB.x = sig * sv[4]; oB.y = sig * sv[5]; oB.z = sig * sv[6]; oB.w = sig * sv[7];
    *(float4*)(qrow + c) = oA;
    *(float4*)(qrow + c + 4) = oB;
}

extern "C" void kernel_launch(void* const* d_in, const int* in_sizes, int n_in,
                              void* d_out, int out_size, void* d_ws, size_t ws_size,
                              hipStream_t stream)
{
    const float* x    = (const float*)d_in[0];
    const float* Wq   = (const float*)d_in[1];
    const float* bq   = (const float*)d_in[2];
    const float* Wk   = (const float*)d_in[3];
    const float* bk   = (const float*)d_in[4];
    const float* Wv   = (const float*)d_in[5];
    const float* bv   = (const float*)d_in[6];
    const float* avgs = (const float*)d_in[7];
    const float* stds = (const float*)d_in[8];
    const float* nx   = (const float*)d_in[9];
    const float* ny   = (const float*)d_in[10];
    const int* img_ids = (const int*)d_in[11];

    float* out = (float*)d_out;

    unsigned short* xbf = (unsigned short*)d_ws;            // 67.1 MB
    unsigned short* wbf = xbf + (size_t)65536 * 512;        // 1.57 MB
    unsigned short* kbf = wbf + (size_t)1536 * 512;         // 67.1 MB
    unsigned short* vbf = kbf + (size_t)65536 * 512;        // 67.1 MB  (total 203 MB)

    cvt_bf16x8<<<16384, 256, 0, stream>>>(x, xbf, 4194304);
    cvt_bf16x8<<<128, 256, 0, stream>>>(Wq, wbf, 32768);
    cvt_bf16x8<<<128, 256, 0, stream>>>(Wk, wbf + 512 * 512, 32768);
    cvt_bf16x8<<<128, 256, 0, stream>>>(Wv, wbf + 2 * 512 * 512, 32768);

    qkv_gemm<<<6144, 256, 0, stream>>>(xbf, wbf, bq, bk, bv, out, kbf, vbf);

    sample_attn<<<16384, 256, 0, stream>>>(out, kbf, vbf, avgs, stds, nx, ny, img_ids);
}

// Round 3
// 363.615 us; speedup vs baseline: 4.2145x; 1.0399x over previous
//
#include <hip/hip_runtime.h>
#include <math.h>

// B=16, P=4096, D=512, G=64, N_IMGS=5000, TEMP=0.01
// M = 65536, K = 512, fused N = 1536 (q|k|v).

typedef __attribute__((ext_vector_type(8))) short s16x8;   // 8 bf16 (4 VGPRs)
typedef __attribute__((ext_vector_type(4))) float f32x4;

__device__ __forceinline__ unsigned short f2bf(float f) {
    unsigned u = __float_as_uint(f);
    u += 0x7FFFu + ((u >> 16) & 1u);   // RNE
    return (unsigned short)(u >> 16);
}

__device__ __forceinline__ void gload_lds16(const void* g, void* l) {
    __builtin_amdgcn_global_load_lds(
        (const __attribute__((address_space(1))) unsigned int*)g,
        (__attribute__((address_space(3))) unsigned int*)l, 16, 0, 0);
}

// ---------- fused fp32 -> bf16 conversion: x then Wq|Wk|Wv ----------
__global__ __launch_bounds__(256) void cvt_all(
    const float* __restrict__ x, const float* __restrict__ Wq,
    const float* __restrict__ Wk, const float* __restrict__ Wv,
    unsigned short* __restrict__ xbf, unsigned short* __restrict__ wbf)
{
    const int i = blockIdx.x * 256 + threadIdx.x;   // 8-elem group index
    const float* src;
    unsigned short* dst;
    size_t off;
    if (i < 4194304) {                 // x: 65536*512 / 8
        src = x; dst = xbf; off = (size_t)i;
    } else {
        int t = i - 4194304;           // 0 .. 98303
        int w = t >> 15;               // 0..2
        off = (size_t)(t & 32767);
        src = (w == 0) ? Wq : (w == 1 ? Wk : Wv);
        dst = wbf + (size_t)w * 512 * 512;
    }
    const float4* s = (const float4*)src + 2 * off;
    float4 a = s[0], b = s[1];
    uint4 o;
    o.x = (unsigned)f2bf(a.x) | ((unsigned)f2bf(a.y) << 16);
    o.y = (unsigned)f2bf(a.z) | ((unsigned)f2bf(a.w) << 16);
    o.z = (unsigned)f2bf(b.x) | ((unsigned)f2bf(b.y) << 16);
    o.w = (unsigned)f2bf(b.z) | ((unsigned)f2bf(b.w) << 16);
    ((uint4*)dst)[off] = o;
}

// ---------- fused QKV GEMM ----------
// 128x128 tile, BK=32, 256 threads (4 waves, 2x2), 4x4 MFMA frags / wave.
// MFMA operands SWAPPED (b,a): D-frag row-index = n, col-index = m, so
// reg quad runs along contiguous n -> vectorized stores.
__global__ __launch_bounds__(256, 3) void qkv_gemm(
    const unsigned short* __restrict__ xbf,   // (65536,512) bf16
    const unsigned short* __restrict__ wbf,   // (1536,512) bf16 (Wq|Wk|Wv)
    const float* __restrict__ bq, const float* __restrict__ bk,
    const float* __restrict__ bv,
    float* __restrict__ qout,                 // (65536,512) f32
    unsigned short* __restrict__ kbf,         // (65536,512) bf16
    unsigned short* __restrict__ vbf)
{
    __shared__ __align__(16) short lds[2][8192];

    const int tid  = threadIdx.x;
    const int lane = tid & 63, wid = tid >> 6;
    const int wr = wid >> 1, wc = wid & 1;

    // Bijective XCD swizzle: 6144 blocks = 8 XCDs * 768. Consecutive wgid
    // (same mt panel, all 12 nt) land on the SAME XCD -> x panel L2-resident.
    const int bid = blockIdx.x;
    const int wgid = (bid & 7) * 768 + (bid >> 3);
    const int mt = wgid / 12, nt = wgid % 12;
    const int m0 = mt * 128, n0 = nt * 128;

    const int srow = tid & 127;
    const int skg  = tid >> 7;
    const unsigned short* a0 = xbf + (size_t)(m0 + srow) * 512 + skg * 8;
    const unsigned short* a1 = a0 + 16;
    const unsigned short* b0 = wbf + (size_t)(n0 + srow) * 512 + skg * 8;
    const unsigned short* b1 = b0 + 16;
    char* ldsc = (char*)lds;
    const int dA0 = tid * 16, dA1 = 4096 + tid * 16;
    const int dB0 = 8192 + tid * 16, dB1 = 12288 + tid * 16;

    f32x4 acc[4][4] = {};   // acc[i][j]: m-frag i, n-frag j (transposed D layout)

    const int abase = (lane >> 4) * 2048 + (wr * 64 + (lane & 15)) * 16;
    const int bbase = 8192 + (lane >> 4) * 2048 + (wc * 64 + (lane & 15)) * 16;

    gload_lds16(a0, ldsc + dA0);
    gload_lds16(a1, ldsc + dA1);
    gload_lds16(b0, ldsc + dB0);
    gload_lds16(b1, ldsc + dB1);

    #pragma unroll
    for (int it = 0; it < 16; ++it) {
        const int buf = it & 1;
        __syncthreads();                       // drains vmcnt: buf's tile ready
        if (it < 15) {
            const int k0 = (it + 1) * 32;
            const int bo = (buf ^ 1) * 16384;
            gload_lds16(a0 + k0, ldsc + bo + dA0);
            gload_lds16(a1 + k0, ldsc + bo + dA1);
            gload_lds16(b0 + k0, ldsc + bo + dB0);
            gload_lds16(b1 + k0, ldsc + bo + dB1);
        }
        const char* lp = ldsc + buf * 16384;
        s16x8 af[4], bfr[4];
        #pragma unroll
        for (int i = 0; i < 4; ++i) af[i]  = *(const s16x8*)(lp + abase + i * 256);
        #pragma unroll
        for (int j = 0; j < 4; ++j) bfr[j] = *(const s16x8*)(lp + bbase + j * 256);
        #pragma unroll
        for (int i = 0; i < 4; ++i)
            #pragma unroll
            for (int j = 0; j < 4; ++j)
                acc[i][j] = __builtin_amdgcn_mfma_f32_16x16x32_bf16(
                    bfr[j], af[i], acc[i][j], 0, 0, 0);   // SWAPPED
    }

    // Epilogue: per lane m = lane&15 (fixed per frag-i), n = base + (lane>>4)*4 + r.
    const int sel = nt >> 2;                   // 0=q, 1=k, 2=v
    const float* bias = sel == 0 ? bq : (sel == 1 ? bk : bv);
    const int rowg  = m0 + wr * 64 + (lane & 15);           // + i*16
    const int colg  = (n0 & 511) + wc * 64 + (lane >> 4) * 4;  // + j*16

    if (sel == 0) {
        #pragma unroll
        for (int j = 0; j < 4; ++j) {
            const float4 b4 = *(const float4*)&bias[colg + j * 16];
            #pragma unroll
            for (int i = 0; i < 4; ++i) {
                float4 o;
                o.x = acc[i][j][0] + b4.x; o.y = acc[i][j][1] + b4.y;
                o.z = acc[i][j][2] + b4.z; o.w = acc[i][j][3] + b4.w;
                *(float4*)&qout[(size_t)(rowg + i * 16) * 512 + colg + j * 16] = o;
            }
        }
    } else {
        unsigned short* dst = (sel == 1) ? kbf : vbf;
        #pragma unroll
        for (int j = 0; j < 4; ++j) {
            const float4 b4 = *(const float4*)&bias[colg + j * 16];
            #pragma unroll
            for (int i = 0; i < 4; ++i) {
                uint2 o;
                o.x = (unsigned)f2bf(acc[i][j][0] + b4.x)
                    | ((unsigned)f2bf(acc[i][j][1] + b4.y) << 16);
                o.y = (unsigned)f2bf(acc[i][j][2] + b4.z)
                    | ((unsigned)f2bf(acc[i][j][3] + b4.w) << 16);
                *(uint2*)&dst[(size_t)(rowg + i * 16) * 512 + colg + j * 16] = o;
            }
        }
    }
}

// ---------- grid-sample + gated attention ----------
__global__ __launch_bounds__(256) void sample_attn(
    float* __restrict__ qo,                 // (B,P,512) f32: q in, attention out
    const unsigned short* __restrict__ kbf, // (B,P,512) bf16
    const unsigned short* __restrict__ vbf,
    const float* __restrict__ avgs,         // (N_IMGS,2,P)
    const float* __restrict__ stds,
    const float* __restrict__ nx,           // (B,1,P)
    const float* __restrict__ ny,
    const int* __restrict__ img_ids)
{
    const int lane = threadIdx.x & 63;
    const int wid  = threadIdx.x >> 6;
    const int point = (blockIdx.x << 2) + wid;
    const int b = point >> 12;
    const int n = point & 4095;
    const int g1 = n >> 6, g2 = n & 63;
    const int f0 = g1 * 128 + g2 * 2;
    const int id = img_ids[b];

    float g[2];
    #pragma unroll
    for (int c = 0; c < 2; ++c) {
        int f = f0 + c;
        int ch = f >> 12;
        int p  = f & 4095;
        float noise = ch ? ny[(size_t)b * 4096 + p] : nx[(size_t)b * 4096 + p];
        size_t o = ((size_t)id * 2 + ch) * 4096 + p;
        g[c] = tanhf((noise + avgs[o]) * stds[o]);
    }

    float ix = (g[0] + 1.0f) * 32.0f - 0.5f;
    float iy = (g[1] + 1.0f) * 32.0f - 0.5f;
    float fx0 = floorf(ix), fy0 = floorf(iy);
    float wx1 = ix - fx0, wx0 = 1.0f - wx1;
    float wy1 = iy - fy0, wy0 = 1.0f - wy1;
    int x0 = (int)fx0, y0 = (int)fy0;
    int x1 = x0 + 1, y1 = y0 + 1;
    bool vx0 = (x0 >= 0) & (x0 < 64), vx1 = (x1 >= 0) & (x1 < 64);
    bool vy0 = (y0 >= 0) & (y0 < 64), vy1 = (y1 >= 0) & (y1 < 64);
    float w00 = (vx0 & vy0) ? wx0 * wy0 : 0.0f;
    float w10 = (vx1 & vy0) ? wx1 * wy0 : 0.0f;
    float w01 = (vx0 & vy1) ? wx0 * wy1 : 0.0f;
    float w11 = (vx1 & vy1) ? wx1 * wy1 : 0.0f;
    int cx0 = min(max(x0, 0), 63), cx1 = min(max(x1, 0), 63);
    int cy0 = min(max(y0, 0), 63), cy1 = min(max(y1, 0), 63);

    const size_t base = (size_t)b * 4096 * 512;
    const size_t r00 = base + (size_t)(cy0 * 64 + cx0) * 512;
    const size_t r10 = base + (size_t)(cy0 * 64 + cx1) * 512;
    const size_t r01 = base + (size_t)(cy1 * 64 + cx0) * 512;
    const size_t r11 = base + (size_t)(cy1 * 64 + cx1) * 512;

    float* qrow = qo + base + (size_t)n * 512;
    const int c = lane * 8;

    float4 q0 = *(const float4*)(qrow + c);
    float4 q1 = *(const float4*)(qrow + c + 4);

    float sk[8], sv[8];
    {
        uint4 u00k = *(const uint4*)(kbf + r00 + c);
        uint4 u10k = *(const uint4*)(kbf + r10 + c);
        uint4 u01k = *(const uint4*)(kbf + r01 + c);
        uint4 u11k = *(const uint4*)(kbf + r11 + c);
        uint4 u00v = *(const uint4*)(vbf + r00 + c);
        uint4 u10v = *(const uint4*)(vbf + r10 + c);
        uint4 u01v = *(const uint4*)(vbf + r01 + c);
        uint4 u11v = *(const uint4*)(vbf + r11 + c);
        const unsigned* p00k = (const unsigned*)&u00k;
        const unsigned* p10k = (const unsigned*)&u10k;
        const unsigned* p01k = (const unsigned*)&u01k;
        const unsigned* p11k = (const unsigned*)&u11k;
        const unsigned* p00v = (const unsigned*)&u00v;
        const unsigned* p10v = (const unsigned*)&u10v;
        const unsigned* p01v = (const unsigned*)&u01v;
        const unsigned* p11v = (const unsigned*)&u11v;
        #pragma unroll
        for (int t = 0; t < 4; ++t) {
            float a00 = __uint_as_float(p00k[t] << 16);
            float b00 = __uint_as_float(p00k[t] & 0xFFFF0000u);
            float a10 = __uint_as_float(p10k[t] << 16);
            float b10 = __uint_as_float(p10k[t] & 0xFFFF0000u);
            float a01 = __uint_as_float(p01k[t] << 16);
            float b01 = __uint_as_float(p01k[t] & 0xFFFF0000u);
            float a11 = __uint_as_float(p11k[t] << 16);
            float b11 = __uint_as_float(p11k[t] & 0xFFFF0000u);
            sk[2 * t]     = w00 * a00 + w10 * a10 + w01 * a01 + w11 * a11;
            sk[2 * t + 1] = w00 * b00 + w10 * b10 + w01 * b01 + w11 * b11;
            a00 = __uint_as_float(p00v[t] << 16);
            b00 = __uint_as_float(p00v[t] & 0xFFFF0000u);
            a10 = __uint_as_float(p10v[t] << 16);
            b10 = __uint_as_float(p10v[t] & 0xFFFF0000u);
            a01 = __uint_as_float(p01v[t] << 16);
            b01 = __uint_as_float(p01v[t] & 0xFFFF0000u);
            a11 = __uint_as_float(p11v[t] << 16);
            b11 = __uint_as_float(p11v[t] & 0xFFFF0000u);
            sv[2 * t]     = w00 * a00 + w10 * a10 + w01 * a01 + w11 * a11;
            sv[2 * t + 1] = w00 * b00 + w10 * b10 + w01 * b01 + w11 * b11;
        }
    }

    const float qv[8] = {q0.x, q0.y, q0.z, q0.w, q1.x, q1.y, q1.z, q1.w};
    float score = 0.0f;
    #pragma unroll
    for (int t = 0; t < 8; ++t) score += qv[t] * sk[t];
    #pragma unroll
    for (int off = 32; off > 0; off >>= 1)
        score += __shfl_xor(score, off);

    const float sig = 1.0f / (1.0f + expf(-0.01f * score));
    float4 oA, oB;
    oA.x = sig * sv[0]; oA.y = sig * sv[1]; oA.z = sig * sv[2]; oA.w = sig * sv[3];
    oB.x = sig * sv[4]; oB.y = sig * sv[5]; oB.z = sig * sv[6]; oB.w = sig * sv[7];
    *(float4*)(qrow + c) = oA;
    *(float4*)(qrow + c + 4) = oB;
}

extern "C" void kernel_launch(void* const* d_in, const int* in_sizes, int n_in,
                              void* d_out, int out_size, void* d_ws, size_t ws_size,
                              hipStream_t stream)
{
    const float* x    = (const float*)d_in[0];
    const float* Wq   = (const float*)d_in[1];
    const float* bq   = (const float*)d_in[2];
    const float* Wk   = (const float*)d_in[3];
    const float* bk   = (const float*)d_in[4];
    const float* Wv   = (const float*)d_in[5];
    const float* bv   = (const float*)d_in[6];
    const float* avgs = (const float*)d_in[7];
    const float* stds = (const float*)d_in[8];
    const float* nx   = (const float*)d_in[9];
    const float* ny   = (const float*)d_in[10];
    const int* img_ids = (const int*)d_in[11];

    float* out = (float*)d_out;

    unsigned short* xbf = (unsigned short*)d_ws;            // 67.1 MB
    unsigned short* wbf = xbf + (size_t)65536 * 512;        // 1.57 MB
    unsigned short* kbf = wbf + (size_t)1536 * 512;         // 67.1 MB
    unsigned short* vbf = kbf + (size_t)65536 * 512;        // 67.1 MB

    cvt_all<<<16768, 256, 0, stream>>>(x, Wq, Wk, Wv, xbf, wbf);

    qkv_gemm<<<6144, 256, 0, stream>>>(xbf, wbf, bq, bk, bv, out, kbf, vbf);

    sample_attn<<<16384, 256, 0, stream>>>(out, kbf, vbf, avgs, stds, nx, ny, img_ids);
}

// Round 4
// 355.026 us; speedup vs baseline: 4.3165x; 1.0242x over previous
//
#include <hip/hip_runtime.h>
#include <math.h>

// B=16, P=4096, D=512, G=64, N_IMGS=5000, TEMP=0.01
// M = 65536, K = 512, fused N = 1536 (q|k|v).

typedef __attribute__((ext_vector_type(8))) short s16x8;   // 8 bf16 (4 VGPRs)
typedef __attribute__((ext_vector_type(4))) float f32x4;

__device__ __forceinline__ unsigned short f2bf(float f) {
    unsigned u = __float_as_uint(f);
    u += 0x7FFFu + ((u >> 16) & 1u);   // RNE
    return (unsigned short)(u >> 16);
}

__device__ __forceinline__ void gload_lds16(const void* g, void* l) {
    __builtin_amdgcn_global_load_lds(
        (const __attribute__((address_space(1))) unsigned int*)g,
        (__attribute__((address_space(3))) unsigned int*)l, 16, 0, 0);
}

// ---------- fused fp32 -> bf16 conversion: x then Wq|Wk|Wv ----------
__global__ __launch_bounds__(256) void cvt_all(
    const float* __restrict__ x, const float* __restrict__ Wq,
    const float* __restrict__ Wk, const float* __restrict__ Wv,
    unsigned short* __restrict__ xbf, unsigned short* __restrict__ wbf)
{
    const int i = blockIdx.x * 256 + threadIdx.x;   // 8-elem group index
    const float* src;
    unsigned short* dst;
    size_t off;
    if (i < 4194304) {                 // x: 65536*512 / 8
        src = x; dst = xbf; off = (size_t)i;
    } else {
        int t = i - 4194304;           // 0 .. 98303
        int w = t >> 15;               // 0..2
        off = (size_t)(t & 32767);
        src = (w == 0) ? Wq : (w == 1 ? Wk : Wv);
        dst = wbf + (size_t)w * 512 * 512;
    }
    const float4* s = (const float4*)src + 2 * off;
    float4 a = s[0], b = s[1];
    uint4 o;
    o.x = (unsigned)f2bf(a.x) | ((unsigned)f2bf(a.y) << 16);
    o.y = (unsigned)f2bf(a.z) | ((unsigned)f2bf(a.w) << 16);
    o.z = (unsigned)f2bf(b.x) | ((unsigned)f2bf(b.y) << 16);
    o.w = (unsigned)f2bf(b.z) | ((unsigned)f2bf(b.w) << 16);
    ((uint4*)dst)[off] = o;
}

// ---------- fused QKV GEMM ----------
// 256x256 tile, BK=32, 512 threads (8 waves, 2x4), per-wave 128x64 output
// (acc[8][4]). MFMA operands SWAPPED (b,a): reg quad runs along contiguous
// n -> vectorized stores. Same proven 2-phase double-buffer barrier loop.
// LDS per buf: A = [kg:4][row:256][8] bf16 (16 KB) at 0, B same at 16384.
// Buf stride 32768 B, total 64 KB.
__global__ __launch_bounds__(512, 1) void qkv_gemm(
    const unsigned short* __restrict__ xbf,   // (65536,512) bf16
    const unsigned short* __restrict__ wbf,   // (1536,512) bf16 (Wq|Wk|Wv)
    const float* __restrict__ bq, const float* __restrict__ bk,
    const float* __restrict__ bv,
    float* __restrict__ qout,                 // (65536,512) f32
    unsigned short* __restrict__ kbf,         // (65536,512) bf16
    unsigned short* __restrict__ vbf)
{
    __shared__ __align__(16) short lds[2][16384];

    const int tid  = threadIdx.x;
    const int lane = tid & 63, wid = tid >> 6;
    const int wr = wid >> 2, wc = wid & 3;    // 2 (m) x 4 (n) waves

    // Bijective XCD swizzle: 1536 blocks = 8 XCDs * 192. Consecutive wgid
    // (same mt panel, all 6 nt) land on the SAME XCD -> x panel L2-resident.
    const int bid = blockIdx.x;
    const int wgid = (bid & 7) * 192 + (bid >> 3);
    const int mt = wgid / 6, nt = wgid % 6;
    const int m0 = mt * 256, n0 = nt * 256;

    // staging: 4 issues/thread, 16 B each. row = tid&255, kg = tid>>8 (+2).
    const int srow = tid & 255;
    const int skg  = tid >> 8;
    const unsigned short* a0 = xbf + (size_t)(m0 + srow) * 512 + skg * 8;
    const unsigned short* a1 = a0 + 16;       // kg + 2
    const unsigned short* b0 = wbf + (size_t)(n0 + srow) * 512 + skg * 8;
    const unsigned short* b1 = b0 + 16;
    char* ldsc = (char*)lds;
    const int dA0 = tid * 16, dA1 = 8192 + tid * 16;
    const int dB0 = 16384 + tid * 16, dB1 = 24576 + tid * 16;

    f32x4 acc[8][4] = {};   // acc[i][j]: m-frag i, n-frag j (transposed D)

    const int abase = (lane >> 4) * 4096 + (wr * 128 + (lane & 15)) * 16;
    const int bbase = 16384 + (lane >> 4) * 4096 + (wc * 64 + (lane & 15)) * 16;

    gload_lds16(a0, ldsc + dA0);
    gload_lds16(a1, ldsc + dA1);
    gload_lds16(b0, ldsc + dB0);
    gload_lds16(b1, ldsc + dB1);

    #pragma unroll
    for (int it = 0; it < 16; ++it) {
        const int buf = it & 1;
        __syncthreads();                       // drains vmcnt: buf's tile ready
        if (it < 15) {
            const int k0 = (it + 1) * 32;
            const int bo = (buf ^ 1) * 32768;
            gload_lds16(a0 + k0, ldsc + bo + dA0);
            gload_lds16(a1 + k0, ldsc + bo + dA1);
            gload_lds16(b0 + k0, ldsc + bo + dB0);
            gload_lds16(b1 + k0, ldsc + bo + dB1);
        }
        const char* lp = ldsc + buf * 32768;
        s16x8 af[8], bfr[4];
        #pragma unroll
        for (int j = 0; j < 4; ++j) bfr[j] = *(const s16x8*)(lp + bbase + j * 256);
        #pragma unroll
        for (int i = 0; i < 8; ++i) af[i]  = *(const s16x8*)(lp + abase + i * 256);
        #pragma unroll
        for (int i = 0; i < 8; ++i)
            #pragma unroll
            for (int j = 0; j < 4; ++j)
                acc[i][j] = __builtin_amdgcn_mfma_f32_16x16x32_bf16(
                    bfr[j], af[i], acc[i][j], 0, 0, 0);   // SWAPPED
    }

    // Epilogue: per lane m = rowg + i*16, n = colg + j*16 + r (r=0..3).
    const int sel = nt >> 1;                   // 0=q, 1=k, 2=v
    const float* bias = sel == 0 ? bq : (sel == 1 ? bk : bv);
    const int rowg = m0 + wr * 128 + (lane & 15);
    const int colg = (n0 & 511) + wc * 64 + (lane >> 4) * 4;

    if (sel == 0) {
        #pragma unroll
        for (int j = 0; j < 4; ++j) {
            const float4 b4 = *(const float4*)&bias[colg + j * 16];
            #pragma unroll
            for (int i = 0; i < 8; ++i) {
                float4 o;
                o.x = acc[i][j][0] + b4.x; o.y = acc[i][j][1] + b4.y;
                o.z = acc[i][j][2] + b4.z; o.w = acc[i][j][3] + b4.w;
                *(float4*)&qout[(size_t)(rowg + i * 16) * 512 + colg + j * 16] = o;
            }
        }
    } else {
        unsigned short* dst = (sel == 1) ? kbf : vbf;
        #pragma unroll
        for (int j = 0; j < 4; ++j) {
            const float4 b4 = *(const float4*)&bias[colg + j * 16];
            #pragma unroll
            for (int i = 0; i < 8; ++i) {
                uint2 o;
                o.x = (unsigned)f2bf(acc[i][j][0] + b4.x)
                    | ((unsigned)f2bf(acc[i][j][1] + b4.y) << 16);
                o.y = (unsigned)f2bf(acc[i][j][2] + b4.z)
                    | ((unsigned)f2bf(acc[i][j][3] + b4.w) << 16);
                *(uint2*)&dst[(size_t)(rowg + i * 16) * 512 + colg + j * 16] = o;
            }
        }
    }
}

// ---------- grid-sample + gated attention ----------
__global__ __launch_bounds__(256) void sample_attn(
    float* __restrict__ qo,                 // (B,P,512) f32: q in, attention out
    const unsigned short* __restrict__ kbf, // (B,P,512) bf16
    const unsigned short* __restrict__ vbf,
    const float* __restrict__ avgs,         // (N_IMGS,2,P)
    const float* __restrict__ stds,
    const float* __restrict__ nx,           // (B,1,P)
    const float* __restrict__ ny,
    const int* __restrict__ img_ids)
{
    const int lane = threadIdx.x & 63;
    const int wid  = threadIdx.x >> 6;
    const int point = (blockIdx.x << 2) + wid;
    const int b = point >> 12;
    const int n = point & 4095;
    const int g1 = n >> 6, g2 = n & 63;
    const int f0 = g1 * 128 + g2 * 2;
    const int id = img_ids[b];

    float g[2];
    #pragma unroll
    for (int c = 0; c < 2; ++c) {
        int f = f0 + c;
        int ch = f >> 12;
        int p  = f & 4095;
        float noise = ch ? ny[(size_t)b * 4096 + p] : nx[(size_t)b * 4096 + p];
        size_t o = ((size_t)id * 2 + ch) * 4096 + p;
        g[c] = tanhf((noise + avgs[o]) * stds[o]);
    }

    float ix = (g[0] + 1.0f) * 32.0f - 0.5f;
    float iy = (g[1] + 1.0f) * 32.0f - 0.5f;
    float fx0 = floorf(ix), fy0 = floorf(iy);
    float wx1 = ix - fx0, wx0 = 1.0f - wx1;
    float wy1 = iy - fy0, wy0 = 1.0f - wy1;
    int x0 = (int)fx0, y0 = (int)fy0;
    int x1 = x0 + 1, y1 = y0 + 1;
    bool vx0 = (x0 >= 0) & (x0 < 64), vx1 = (x1 >= 0) & (x1 < 64);
    bool vy0 = (y0 >= 0) & (y0 < 64), vy1 = (y1 >= 0) & (y1 < 64);
    float w00 = (vx0 & vy0) ? wx0 * wy0 : 0.0f;
    float w10 = (vx1 & vy0) ? wx1 * wy0 : 0.0f;
    float w01 = (vx0 & vy1) ? wx0 * wy1 : 0.0f;
    float w11 = (vx1 & vy1) ? wx1 * wy1 : 0.0f;
    int cx0 = min(max(x0, 0), 63), cx1 = min(max(x1, 0), 63);
    int cy0 = min(max(y0, 0), 63), cy1 = min(max(y1, 0), 63);

    const size_t base = (size_t)b * 4096 * 512;
    const size_t r00 = base + (size_t)(cy0 * 64 + cx0) * 512;
    const size_t r10 = base + (size_t)(cy0 * 64 + cx1) * 512;
    const size_t r01 = base + (size_t)(cy1 * 64 + cx0) * 512;
    const size_t r11 = base + (size_t)(cy1 * 64 + cx1) * 512;

    float* qrow = qo + base + (size_t)n * 512;
    const int c = lane * 8;

    float4 q0 = *(const float4*)(qrow + c);
    float4 q1 = *(const float4*)(qrow + c + 4);

    float sk[8], sv[8];
    {
        uint4 u00k = *(const uint4*)(kbf + r00 + c);
        uint4 u10k = *(const uint4*)(kbf + r10 + c);
        uint4 u01k = *(const uint4*)(kbf + r01 + c);
        uint4 u11k = *(const uint4*)(kbf + r11 + c);
        uint4 u00v = *(const uint4*)(vbf + r00 + c);
        uint4 u10v = *(const uint4*)(vbf + r10 + c);
        uint4 u01v = *(const uint4*)(vbf + r01 + c);
        uint4 u11v = *(const uint4*)(vbf + r11 + c);
        const unsigned* p00k = (const unsigned*)&u00k;
        const unsigned* p10k = (const unsigned*)&u10k;
        const unsigned* p01k = (const unsigned*)&u01k;
        const unsigned* p11k = (const unsigned*)&u11k;
        const unsigned* p00v = (const unsigned*)&u00v;
        const unsigned* p10v = (const unsigned*)&u10v;
        const unsigned* p01v = (const unsigned*)&u01v;
        const unsigned* p11v = (const unsigned*)&u11v;
        #pragma unroll
        for (int t = 0; t < 4; ++t) {
            float a00 = __uint_as_float(p00k[t] << 16);
            float b00 = __uint_as_float(p00k[t] & 0xFFFF0000u);
            float a10 = __uint_as_float(p10k[t] << 16);
            float b10 = __uint_as_float(p10k[t] & 0xFFFF0000u);
            float a01 = __uint_as_float(p01k[t] << 16);
            float b01 = __uint_as_float(p01k[t] & 0xFFFF0000u);
            float a11 = __uint_as_float(p11k[t] << 16);
            float b11 = __uint_as_float(p11k[t] & 0xFFFF0000u);
            sk[2 * t]     = w00 * a00 + w10 * a10 + w01 * a01 + w11 * a11;
            sk[2 * t + 1] = w00 * b00 + w10 * b10 + w01 * b01 + w11 * b11;
            a00 = __uint_as_float(p00v[t] << 16);
            b00 = __uint_as_float(p00v[t] & 0xFFFF0000u);
            a10 = __uint_as_float(p10v[t] << 16);
            b10 = __uint_as_float(p10v[t] & 0xFFFF0000u);
            a01 = __uint_as_float(p01v[t] << 16);
            b01 = __uint_as_float(p01v[t] & 0xFFFF0000u);
            a11 = __uint_as_float(p11v[t] << 16);
            b11 = __uint_as_float(p11v[t] & 0xFFFF0000u);
            sv[2 * t]     = w00 * a00 + w10 * a10 + w01 * a01 + w11 * a11;
            sv[2 * t + 1] = w00 * b00 + w10 * b10 + w01 * b01 + w11 * b11;
        }
    }

    const float qv[8] = {q0.x, q0.y, q0.z, q0.w, q1.x, q1.y, q1.z, q1.w};
    float score = 0.0f;
    #pragma unroll
    for (int t = 0; t < 8; ++t) score += qv[t] * sk[t];
    #pragma unroll
    for (int off = 32; off > 0; off >>= 1)
        score += __shfl_xor(score, off);

    const float sig = 1.0f / (1.0f + expf(-0.01f * score));
    float4 oA, oB;
    oA.x = sig * sv[0]; oA.y = sig * sv[1]; oA.z = sig * sv[2]; oA.w = sig * sv[3];
    oB.x = sig * sv[4]; oB.y = sig * sv[5]; oB.z = sig * sv[6]; oB.w = sig * sv[7];
    *(float4*)(qrow + c) = oA;
    *(float4*)(qrow + c + 4) = oB;
}

extern "C" void kernel_launch(void* const* d_in, const int* in_sizes, int n_in,
                              void* d_out, int out_size, void* d_ws, size_t ws_size,
                              hipStream_t stream)
{
    const float* x    = (const float*)d_in[0];
    const float* Wq   = (const float*)d_in[1];
    const float* bq   = (const float*)d_in[2];
    const float* Wk   = (const float*)d_in[3];
    const float* bk   = (const float*)d_in[4];
    const float* Wv   = (const float*)d_in[5];
    const float* bv   = (const float*)d_in[6];
    const float* avgs = (const float*)d_in[7];
    const float* stds = (const float*)d_in[8];
    const float* nx   = (const float*)d_in[9];
    const float* ny   = (const float*)d_in[10];
    const int* img_ids = (const int*)d_in[11];

    float* out = (float*)d_out;

    unsigned short* xbf = (unsigned short*)d_ws;            // 67.1 MB
    unsigned short* wbf = xbf + (size_t)65536 * 512;        // 1.57 MB
    unsigned short* kbf = wbf + (size_t)1536 * 512;         // 67.1 MB
    unsigned short* vbf = kbf + (size_t)65536 * 512;        // 67.1 MB

    cvt_all<<<16768, 256, 0, stream>>>(x, Wq, Wk, Wv, xbf, wbf);

    qkv_gemm<<<1536, 512, 0, stream>>>(xbf, wbf, bq, bk, bv, out, kbf, vbf);

    sample_attn<<<16384, 256, 0, stream>>>(out, kbf, vbf, avgs, stds, nx, ny, img_ids);
}

// Round 5
// 319.820 us; speedup vs baseline: 4.7916x; 1.1101x over previous
//
#include <hip/hip_runtime.h>
#include <math.h>

// B=16, P=4096, D=512, G=64, N_IMGS=5000, TEMP=0.01
// M = 65536, K = 512, fused N = 1536 (q|k|v).

typedef __attribute__((ext_vector_type(8))) short s16x8;   // 8 bf16 (4 VGPRs)
typedef __attribute__((ext_vector_type(4))) float f32x4;

__device__ __forceinline__ unsigned short f2bf(float f) {
    unsigned u = __float_as_uint(f);
    u += 0x7FFFu + ((u >> 16) & 1u);   // RNE
    return (unsigned short)(u >> 16);
}

__device__ __forceinline__ void gload_lds16(const void* g, void* l) {
    __builtin_amdgcn_global_load_lds(
        (const __attribute__((address_space(1))) unsigned int*)g,
        (__attribute__((address_space(3))) unsigned int*)l, 16, 0, 0);
}

// ---------- fused fp32 -> bf16 conversion: x then Wq|Wk|Wv ----------
__global__ __launch_bounds__(256) void cvt_all(
    const float* __restrict__ x, const float* __restrict__ Wq,
    const float* __restrict__ Wk, const float* __restrict__ Wv,
    unsigned short* __restrict__ xbf, unsigned short* __restrict__ wbf)
{
    const int i = blockIdx.x * 256 + threadIdx.x;   // 8-elem group index
    const float* src;
    unsigned short* dst;
    size_t off;
    if (i < 4194304) {                 // x: 65536*512 / 8
        src = x; dst = xbf; off = (size_t)i;
    } else {
        int t = i - 4194304;           // 0 .. 98303
        int w = t >> 15;               // 0..2
        off = (size_t)(t & 32767);
        src = (w == 0) ? Wq : (w == 1 ? Wk : Wv);
        dst = wbf + (size_t)w * 512 * 512;
    }
    const float4* s = (const float4*)src + 2 * off;
    float4 a = s[0], b = s[1];
    uint4 o;
    o.x = (unsigned)f2bf(a.x) | ((unsigned)f2bf(a.y) << 16);
    o.y = (unsigned)f2bf(a.z) | ((unsigned)f2bf(a.w) << 16);
    o.z = (unsigned)f2bf(b.x) | ((unsigned)f2bf(b.y) << 16);
    o.w = (unsigned)f2bf(b.z) | ((unsigned)f2bf(b.w) << 16);
    ((uint4*)dst)[off] = o;
}

// ---------- fused QKV GEMM, phase-split + counted-vmcnt pipeline ----------
// 256x256 tile, BK=32, 512 threads (8 waves 2x4), per-wave 128x64 (acc[8][4]).
// LDS: 4-ring of 32 KiB K-tile buffers (A 16K + B 16K each) = 128 KiB.
// Tile t: compute from buf[t&3]; stage tile t+3 into buf[(t+3)&3]=buf[(t-1)&3]
// (fully consumed at the barrier that opens tile t -> race-free by barrier).
// vmcnt(8) once per tile = {A,B}x{t+1,t+2} allowed outstanding; never 0
// until the final tiles. Raw s_barrier (no compiler vmcnt(0) drain).
template<int T, int NVM, bool STAGE>
__device__ __forceinline__ void tile_step(
    char* ldsc, const unsigned short* aP, const unsigned short* bP,
    int tid, int abase, int bbase, f32x4 (&acc)[8][4])
{
    asm volatile("s_waitcnt vmcnt(%0)" :: "i"(NVM) : "memory");
    __builtin_amdgcn_s_barrier();            // all waves confirmed tile T landed
    __builtin_amdgcn_sched_barrier(0);
    const char* lp = ldsc + (T & 3) * 32768;
    s16x8 bfr[4], af[4];
    #pragma unroll
    for (int j = 0; j < 4; ++j) bfr[j] = *(const s16x8*)(lp + bbase + j * 256);
    #pragma unroll
    for (int u = 0; u < 4; ++u) af[u] = *(const s16x8*)(lp + abase + u * 256);
    if (STAGE) {                             // A-half of tile T+3
        const int bo = ((T + 3) & 3) * 32768;
        gload_lds16(aP + (T + 3) * 32,      ldsc + bo + tid * 16);
        gload_lds16(aP + (T + 3) * 32 + 16, ldsc + bo + 8192 + tid * 16);
    }
    __builtin_amdgcn_s_barrier();
    asm volatile("s_waitcnt lgkmcnt(0)");
    __builtin_amdgcn_sched_barrier(0);
    __builtin_amdgcn_s_setprio(1);
    #pragma unroll
    for (int u = 0; u < 4; ++u)
        #pragma unroll
        for (int j = 0; j < 4; ++j)
            acc[u][j] = __builtin_amdgcn_mfma_f32_16x16x32_bf16(
                bfr[j], af[u], acc[u][j], 0, 0, 0);
    __builtin_amdgcn_s_setprio(0);
    __builtin_amdgcn_s_barrier();
    __builtin_amdgcn_sched_barrier(0);
    #pragma unroll
    for (int u = 0; u < 4; ++u)              // A rows 64..127 of wave
        af[u] = *(const s16x8*)(lp + abase + 1024 + u * 256);
    if (STAGE) {                             // B-half of tile T+3
        const int bo = ((T + 3) & 3) * 32768;
        gload_lds16(bP + (T + 3) * 32,      ldsc + bo + 16384 + tid * 16);
        gload_lds16(bP + (T + 3) * 32 + 16, ldsc + bo + 24576 + tid * 16);
    }
    __builtin_amdgcn_s_barrier();
    asm volatile("s_waitcnt lgkmcnt(0)");
    __builtin_amdgcn_sched_barrier(0);
    __builtin_amdgcn_s_setprio(1);
    #pragma unroll
    for (int u = 0; u < 4; ++u)
        #pragma unroll
        for (int j = 0; j < 4; ++j)
            acc[4 + u][j] = __builtin_amdgcn_mfma_f32_16x16x32_bf16(
                bfr[j], af[u], acc[4 + u][j], 0, 0, 0);
    __builtin_amdgcn_s_setprio(0);
}

__global__ __launch_bounds__(512, 1) void qkv_gemm(
    const unsigned short* __restrict__ xbf,   // (65536,512) bf16
    const unsigned short* __restrict__ wbf,   // (1536,512) bf16 (Wq|Wk|Wv)
    const float* __restrict__ bq, const float* __restrict__ bk,
    const float* __restrict__ bv,
    float* __restrict__ qout,                 // (65536,512) f32
    unsigned short* __restrict__ kbf,         // (65536,512) bf16
    unsigned short* __restrict__ vbf)
{
    __shared__ __align__(16) short lds[4][16384];   // 128 KiB ring

    const int tid  = threadIdx.x;
    const int lane = tid & 63, wid = tid >> 6;
    const int wr = wid >> 2, wc = wid & 3;    // 2 (m) x 4 (n) waves

    // Bijective XCD swizzle: 1536 blocks = 8 XCDs * 192.
    const int bid = blockIdx.x;
    const int wgid = (bid & 7) * 192 + (bid >> 3);
    const int mt = wgid / 6, nt = wgid % 6;
    const int m0 = mt * 256, n0 = nt * 256;

    // staging: thread covers LDS bytes tid*16 of each 8 KiB kg-pair region.
    const int srow = tid & 255;
    const unsigned short* aP = xbf + (size_t)(m0 + srow) * 512 + (tid >> 8) * 8;
    const unsigned short* bP = wbf + (size_t)(n0 + srow) * 512 + (tid >> 8) * 8;
    char* ldsc = (char*)lds;

    f32x4 acc[8][4] = {};

    const int abase = (lane >> 4) * 4096 + (wr * 128 + (lane & 15)) * 16;
    const int bbase = 16384 + (lane >> 4) * 4096 + (wc * 64 + (lane & 15)) * 16;

    // prologue: stage tiles 0,1,2 (tile-major order: A(t) pair then B(t) pair)
    #pragma unroll
    for (int t = 0; t < 3; ++t) {
        const int bo = t * 32768;
        gload_lds16(aP + t * 32,      ldsc + bo + tid * 16);
        gload_lds16(aP + t * 32 + 16, ldsc + bo + 8192 + tid * 16);
        gload_lds16(bP + t * 32,      ldsc + bo + 16384 + tid * 16);
        gload_lds16(bP + t * 32 + 16, ldsc + bo + 24576 + tid * 16);
    }

    tile_step< 0, 8, true >(ldsc, aP, bP, tid, abase, bbase, acc);
    tile_step< 1, 8, true >(ldsc, aP, bP, tid, abase, bbase, acc);
    tile_step< 2, 8, true >(ldsc, aP, bP, tid, abase, bbase, acc);
    tile_step< 3, 8, true >(ldsc, aP, bP, tid, abase, bbase, acc);
    tile_step< 4, 8, true >(ldsc, aP, bP, tid, abase, bbase, acc);
    tile_step< 5, 8, true >(ldsc, aP, bP, tid, abase, bbase, acc);
    tile_step< 6, 8, true >(ldsc, aP, bP, tid, abase, bbase, acc);
    tile_step< 7, 8, true >(ldsc, aP, bP, tid, abase, bbase, acc);
    tile_step< 8, 8, true >(ldsc, aP, bP, tid, abase, bbase, acc);
    tile_step< 9, 8, true >(ldsc, aP, bP, tid, abase, bbase, acc);
    tile_step<10, 8, true >(ldsc, aP, bP, tid, abase, bbase, acc);
    tile_step<11, 8, true >(ldsc, aP, bP, tid, abase, bbase, acc);
    tile_step<12, 8, true >(ldsc, aP, bP, tid, abase, bbase, acc);
    tile_step<13, 8, false>(ldsc, aP, bP, tid, abase, bbase, acc);
    tile_step<14, 4, false>(ldsc, aP, bP, tid, abase, bbase, acc);
    tile_step<15, 0, false>(ldsc, aP, bP, tid, abase, bbase, acc);

    // Epilogue: per lane m = rowg + i*16, n = colg + j*16 + r (r=0..3).
    const int sel = nt >> 1;                   // 0=q, 1=k, 2=v
    const float* bias = sel == 0 ? bq : (sel == 1 ? bk : bv);
    const int rowg = m0 + wr * 128 + (lane & 15);
    const int colg = (n0 & 511) + wc * 64 + (lane >> 4) * 4;

    if (sel == 0) {
        #pragma unroll
        for (int j = 0; j < 4; ++j) {
            const float4 b4 = *(const float4*)&bias[colg + j * 16];
            #pragma unroll
            for (int i = 0; i < 8; ++i) {
                float4 o;
                o.x = acc[i][j][0] + b4.x; o.y = acc[i][j][1] + b4.y;
                o.z = acc[i][j][2] + b4.z; o.w = acc[i][j][3] + b4.w;
                *(float4*)&qout[(size_t)(rowg + i * 16) * 512 + colg + j * 16] = o;
            }
        }
    } else {
        unsigned short* dst = (sel == 1) ? kbf : vbf;
        #pragma unroll
        for (int j = 0; j < 4; ++j) {
            const float4 b4 = *(const float4*)&bias[colg + j * 16];
            #pragma unroll
            for (int i = 0; i < 8; ++i) {
                uint2 o;
                o.x = (unsigned)f2bf(acc[i][j][0] + b4.x)
                    | ((unsigned)f2bf(acc[i][j][1] + b4.y) << 16);
                o.y = (unsigned)f2bf(acc[i][j][2] + b4.z)
                    | ((unsigned)f2bf(acc[i][j][3] + b4.w) << 16);
                *(uint2*)&dst[(size_t)(rowg + i * 16) * 512 + colg + j * 16] = o;
            }
        }
    }
}

// ---------- grid-sample + gated attention ----------
__global__ __launch_bounds__(256) void sample_attn(
    float* __restrict__ qo,                 // (B,P,512) f32: q in, attention out
    const unsigned short* __restrict__ kbf, // (B,P,512) bf16
    const unsigned short* __restrict__ vbf,
    const float* __restrict__ avgs,         // (N_IMGS,2,P)
    const float* __restrict__ stds,
    const float* __restrict__ nx,           // (B,1,P)
    const float* __restrict__ ny,
    const int* __restrict__ img_ids)
{
    const int lane = threadIdx.x & 63;
    const int wid  = threadIdx.x >> 6;
    const int point = (blockIdx.x << 2) + wid;
    const int b = point >> 12;
    const int n = point & 4095;
    const int g1 = n >> 6, g2 = n & 63;
    const int f0 = g1 * 128 + g2 * 2;
    const int id = img_ids[b];

    float g[2];
    #pragma unroll
    for (int c = 0; c < 2; ++c) {
        int f = f0 + c;
        int ch = f >> 12;
        int p  = f & 4095;
        float noise = ch ? ny[(size_t)b * 4096 + p] : nx[(size_t)b * 4096 + p];
        size_t o = ((size_t)id * 2 + ch) * 4096 + p;
        g[c] = tanhf((noise + avgs[o]) * stds[o]);
    }

    float ix = (g[0] + 1.0f) * 32.0f - 0.5f;
    float iy = (g[1] + 1.0f) * 32.0f - 0.5f;
    float fx0 = floorf(ix), fy0 = floorf(iy);
    float wx1 = ix - fx0, wx0 = 1.0f - wx1;
    float wy1 = iy - fy0, wy0 = 1.0f - wy1;
    int x0 = (int)fx0, y0 = (int)fy0;
    int x1 = x0 + 1, y1 = y0 + 1;
    bool vx0 = (x0 >= 0) & (x0 < 64), vx1 = (x1 >= 0) & (x1 < 64);
    bool vy0 = (y0 >= 0) & (y0 < 64), vy1 = (y1 >= 0) & (y1 < 64);
    float w00 = (vx0 & vy0) ? wx0 * wy0 : 0.0f;
    float w10 = (vx1 & vy0) ? wx1 * wy0 : 0.0f;
    float w01 = (vx0 & vy1) ? wx0 * wy1 : 0.0f;
    float w11 = (vx1 & vy1) ? wx1 * wy1 : 0.0f;
    int cx0 = min(max(x0, 0), 63), cx1 = min(max(x1, 0), 63);
    int cy0 = min(max(y0, 0), 63), cy1 = min(max(y1, 0), 63);

    const size_t base = (size_t)b * 4096 * 512;
    const size_t r00 = base + (size_t)(cy0 * 64 + cx0) * 512;
    const size_t r10 = base + (size_t)(cy0 * 64 + cx1) * 512;
    const size_t r01 = base + (size_t)(cy1 * 64 + cx0) * 512;
    const size_t r11 = base + (size_t)(cy1 * 64 + cx1) * 512;

    float* qrow = qo + base + (size_t)n * 512;
    const int c = lane * 8;

    float4 q0 = *(const float4*)(qrow + c);
    float4 q1 = *(const float4*)(qrow + c + 4);

    float sk[8], sv[8];
    {
        uint4 u00k = *(const uint4*)(kbf + r00 + c);
        uint4 u10k = *(const uint4*)(kbf + r10 + c);
        uint4 u01k = *(const uint4*)(kbf + r01 + c);
        uint4 u11k = *(const uint4*)(kbf + r11 + c);
        uint4 u00v = *(const uint4*)(vbf + r00 + c);
        uint4 u10v = *(const uint4*)(vbf + r10 + c);
        uint4 u01v = *(const uint4*)(vbf + r01 + c);
        uint4 u11v = *(const uint4*)(vbf + r11 + c);
        const unsigned* p00k = (const unsigned*)&u00k;
        const unsigned* p10k = (const unsigned*)&u10k;
        const unsigned* p01k = (const unsigned*)&u01k;
        const unsigned* p11k = (const unsigned*)&u11k;
        const unsigned* p00v = (const unsigned*)&u00v;
        const unsigned* p10v = (const unsigned*)&u10v;
        const unsigned* p01v = (const unsigned*)&u01v;
        const unsigned* p11v = (const unsigned*)&u11v;
        #pragma unroll
        for (int t = 0; t < 4; ++t) {
            float a00 = __uint_as_float(p00k[t] << 16);
            float b00 = __uint_as_float(p00k[t] & 0xFFFF0000u);
            float a10 = __uint_as_float(p10k[t] << 16);
            float b10 = __uint_as_float(p10k[t] & 0xFFFF0000u);
            float a01 = __uint_as_float(p01k[t] << 16);
            float b01 = __uint_as_float(p01k[t] & 0xFFFF0000u);
            float a11 = __uint_as_float(p11k[t] << 16);
            float b11 = __uint_as_float(p11k[t] & 0xFFFF0000u);
            sk[2 * t]     = w00 * a00 + w10 * a10 + w01 * a01 + w11 * a11;
            sk[2 * t + 1] = w00 * b00 + w10 * b10 + w01 * b01 + w11 * b11;
            a00 = __uint_as_float(p00v[t] << 16);
            b00 = __uint_as_float(p00v[t] & 0xFFFF0000u);
            a10 = __uint_as_float(p10v[t] << 16);
            b10 = __uint_as_float(p10v[t] & 0xFFFF0000u);
            a01 = __uint_as_float(p01v[t] << 16);
            b01 = __uint_as_float(p01v[t] & 0xFFFF0000u);
            a11 = __uint_as_float(p11v[t] << 16);
            b11 = __uint_as_float(p11v[t] & 0xFFFF0000u);
            sv[2 * t]     = w00 * a00 + w10 * a10 + w01 * a01 + w11 * a11;
            sv[2 * t + 1] = w00 * b00 + w10 * b10 + w01 * b01 + w11 * b11;
        }
    }

    const float qv[8] = {q0.x, q0.y, q0.z, q0.w, q1.x, q1.y, q1.z, q1.w};
    float score = 0.0f;
    #pragma unroll
    for (int t = 0; t < 8; ++t) score += qv[t] * sk[t];
    #pragma unroll
    for (int off = 32; off > 0; off >>= 1)
        score += __shfl_xor(score, off);

    const float sig = 1.0f / (1.0f + expf(-0.01f * score));
    float4 oA, oB;
    oA.x = sig * sv[0]; oA.y = sig * sv[1]; oA.z = sig * sv[2]; oA.w = sig * sv[3];
    oB.x = sig * sv[4]; oB.y = sig * sv[5]; oB.z = sig * sv[6]; oB.w = sig * sv[7];
    *(float4*)(qrow + c) = oA;
    *(float4*)(qrow + c + 4) = oB;
}

extern "C" void kernel_launch(void* const* d_in, const int* in_sizes, int n_in,
                              void* d_out, int out_size, void* d_ws, size_t ws_size,
                              hipStream_t stream)
{
    const float* x    = (const float*)d_in[0];
    const float* Wq   = (const float*)d_in[1];
    const float* bq   = (const float*)d_in[2];
    const float* Wk   = (const float*)d_in[3];
    const float* bk   = (const float*)d_in[4];
    const float* Wv   = (const float*)d_in[5];
    const float* bv   = (const float*)d_in[6];
    const float* avgs = (const float*)d_in[7];
    const float* stds = (const float*)d_in[8];
    const float* nx   = (const float*)d_in[9];
    const float* ny   = (const float*)d_in[10];
    const int* img_ids = (const int*)d_in[11];

    float* out = (float*)d_out;

    unsigned short* xbf = (unsigned short*)d_ws;            // 67.1 MB
    unsigned short* wbf = xbf + (size_t)65536 * 512;        // 1.57 MB
    unsigned short* kbf = wbf + (size_t)1536 * 512;         // 67.1 MB
    unsigned short* vbf = kbf + (size_t)65536 * 512;        // 67.1 MB

    cvt_all<<<16768, 256, 0, stream>>>(x, Wq, Wk, Wv, xbf, wbf);

    qkv_gemm<<<1536, 512, 0, stream>>>(xbf, wbf, bq, bk, bv, out, kbf, vbf);

    sample_attn<<<16384, 256, 0, stream>>>(out, kbf, vbf, avgs, stds, nx, ny, img_ids);
}